// Round 1
// baseline (22208.372 us; speedup 1.0000x reference)
//
#include <hip/hip_runtime.h>
#include <hip/hip_bf16.h>

typedef __attribute__((ext_vector_type(8))) short bf16x8;
typedef __attribute__((ext_vector_type(4))) float f32x4;

#define B_N 128
#define T_N 512
#define D_N 1024
#define H_N 1024

// step-kernel tiling
#define MT 64      // batch rows per block
#define JT 16      // j columns per block (x4 gates = 64 effective GEMM cols)
#define NEFF 64
#define BK 64
#define NKB 32     // (D+H)/BK = 2048/64
#define LDP 72     // padded LDS leading dim (bf16 elems): 144B rows -> 2-way bank alias only

// bf16 via raw ushort to avoid __hip_bfloat16 class/union issues
__device__ __forceinline__ unsigned short f2bf(float f) {
  unsigned int u = __float_as_uint(f);
  unsigned int r = (u + 0x7FFFu + ((u >> 16) & 1u)) >> 16;
  return (unsigned short)r;
}

// Pack Wh (k<1024) and Wx (k>=1024) into bf16, pre-gathered per j-block:
// Wp[jb][kb][c][kk], c = g*16 + jj  (column c of the effective GEMM),
// element = Wcomb[kb*64+kk][g*1024 + jb*16 + jj]
__global__ __launch_bounds__(256) void pack_w_kernel(
    const float* __restrict__ Wx, const float* __restrict__ Wh,
    unsigned short* __restrict__ Wp)
{
  int idx = blockIdx.x * 256 + threadIdx.x;   // 2^23 total
  int kk = idx & 63;
  int c  = (idx >> 6) & 63;
  int kb = (idx >> 12) & 31;
  int jb = idx >> 17;
  int g  = c >> 4;
  int j  = jb * 16 + (c & 15);
  int k  = kb * 64 + kk;
  float v = (k < H_N) ? Wh[((size_t)g * H_N + k) * H_N + j]
                      : Wx[((size_t)g * D_N + (k - H_N)) * H_N + j];
  Wp[idx] = f2bf(v);
}

// One timestep: gates = [h_t ; x_t] @ Wcomb + b ; elementwise LSTM update fused.
__global__ __launch_bounds__(256) void step_kernel(
    const float* __restrict__ x,
    const unsigned short* __restrict__ Wp,
    const float* __restrict__ bias,
    const unsigned short* __restrict__ h_cur,
    unsigned short* __restrict__ h_nxt,
    float* __restrict__ cbuf,
    float* __restrict__ out,
    int t, int last)
{
  __shared__ alignas(16) char smem[18432];
  unsigned short (*As)[LDP] = (unsigned short (*)[LDP])smem;            // 64x72 bf16
  unsigned short (*Bs)[LDP] = (unsigned short (*)[LDP])(smem + 9216);   // 64x72 bf16 (transposed: [col][k])

  const int jb   = blockIdx.x;     // 0..63 : j block
  const int rb   = blockIdx.y;     // 0..1  : batch-row block
  const int tid  = threadIdx.x;
  const int lane = tid & 63;
  const int wid  = tid >> 6;
  const int wr   = wid >> 1;       // wave row (0..1), 32 rows each
  const int wc   = wid & 1;        // wave col (0..1), 32 eff-cols each
  const int row0 = rb * MT;

  f32x4 acc[2][2] = {};

  for (int kb = 0; kb < NKB; ++kb) {
    const int kbase = kb * BK;
    // ---- stage A: [64 rows][64 k] bf16. k<1024 from h (bf16), else from x (f32->bf16)
    #pragma unroll
    for (int rep = 0; rep < 2; ++rep) {
      int ch = rep * 256 + tid;          // 512 chunks of 8 bf16
      int m  = ch >> 3;
      int k8 = (ch & 7) * 8;
      int k  = kbase + k8;
      if (k < H_N) {
        *(bf16x8*)&As[m][k8] = *(const bf16x8*)(h_cur + (size_t)(row0 + m) * H_N + k);
      } else {
        const float* xp = x + ((size_t)(row0 + m) * T_N + t) * D_N + (k - H_N);
        float4 f0 = *(const float4*)xp;
        float4 f1 = *(const float4*)(xp + 4);
        union { bf16x8 v; unsigned short s[8]; } u;
        u.s[0] = f2bf(f0.x); u.s[1] = f2bf(f0.y);
        u.s[2] = f2bf(f0.z); u.s[3] = f2bf(f0.w);
        u.s[4] = f2bf(f1.x); u.s[5] = f2bf(f1.y);
        u.s[6] = f2bf(f1.z); u.s[7] = f2bf(f1.w);
        *(bf16x8*)&As[m][k8] = u.v;
      }
    }
    // ---- stage B: contiguous copy of the pre-gathered 8KB tile (layout matches LDS [c][k])
    const unsigned short* wsrc = Wp + ((size_t)(jb * NKB + kb) << 12);
    #pragma unroll
    for (int rep = 0; rep < 2; ++rep) {
      int ch = rep * 256 + tid;
      int cN = ch >> 3;
      int k8 = (ch & 7) * 8;
      *(bf16x8*)&Bs[cN][k8] = *(const bf16x8*)(wsrc + cN * 64 + k8);
    }
    __syncthreads();
    // ---- MFMA: 2 k-steps of 32 per staged block
    #pragma unroll
    for (int ks = 0; ks < 2; ++ks) {
      const int kq = ks * 32 + (lane >> 4) * 8;
      bf16x8 af[2], bfr[2];
      #pragma unroll
      for (int mi = 0; mi < 2; ++mi)
        af[mi] = *(const bf16x8*)&As[wr * 32 + mi * 16 + (lane & 15)][kq];
      #pragma unroll
      for (int ni = 0; ni < 2; ++ni)
        bfr[ni] = *(const bf16x8*)&Bs[wc * 32 + ni * 16 + (lane & 15)][kq];
      #pragma unroll
      for (int mi = 0; mi < 2; ++mi)
        #pragma unroll
        for (int ni = 0; ni < 2; ++ni)
          acc[mi][ni] = __builtin_amdgcn_mfma_f32_16x16x32_bf16(
              af[mi], bfr[ni], acc[mi][ni], 0, 0, 0);
    }
    __syncthreads();
  }

  // ---- epilogue: exchange gates through LDS so each thread sees all 4 gates of (b,j)
  float* gt = (float*)smem;   // [64][64] f32 = 16KB (reuses As/Bs)
  #pragma unroll
  for (int mi = 0; mi < 2; ++mi)
    #pragma unroll
    for (int ni = 0; ni < 2; ++ni)
      #pragma unroll
      for (int r = 0; r < 4; ++r) {
        int row = wr * 32 + mi * 16 + (lane >> 4) * 4 + r;   // C/D: row=(lane>>4)*4+reg
        int col = wc * 32 + ni * 16 + (lane & 15);           //      col=lane&15
        gt[row * 64 + col] = acc[mi][ni][r];
      }
  __syncthreads();

  #pragma unroll
  for (int rep = 0; rep < 4; ++rep) {
    int it = rep * 256 + tid;        // 1024 (b,j) items
    int m  = it >> 4;
    int jj = it & 15;
    int bg = row0 + m;
    int j  = jb * JT + jj;
    float gi = gt[m * 64 +      jj] + bias[j];
    float gf = gt[m * 64 + 16 + jj] + bias[H_N + j];
    float go = gt[m * 64 + 32 + jj] + bias[2 * H_N + j];
    float gu = gt[m * 64 + 48 + jj] + bias[3 * H_N + j];
    float iv = 1.f / (1.f + expf(-gi));
    float fv = 1.f / (1.f + expf(-gf));
    float ov = 1.f / (1.f + expf(-go));
    float uv = tanhf(gu);
    size_t off = (size_t)bg * H_N + j;
    float cn = fv * cbuf[off] + iv * uv;
    cbuf[off] = cn;
    float hn = ov * tanhf(cn);
    h_nxt[off] = f2bf(hn);
    if (last) out[off] = hn;
  }
}

extern "C" void kernel_launch(void* const* d_in, const int* in_sizes, int n_in,
                              void* d_out, int out_size, void* d_ws, size_t ws_size,
                              hipStream_t stream) {
  const float* x    = (const float*)d_in[0];
  // d_in[1] = adjacency (unused by the reference forward)
  const float* Wx   = (const float*)d_in[2];
  const float* Wh   = (const float*)d_in[3];
  const float* bias = (const float*)d_in[4];
  float* out = (float*)d_out;

  // ws layout: Wp (16,777,216 B) | h0 (262,144 B) | h1 (262,144 B) | c (524,288 B)
  char* ws = (char*)d_ws;
  unsigned short* Wp = (unsigned short*)ws;
  unsigned short* h0 = (unsigned short*)(ws + 16777216);
  unsigned short* h1 = h0 + B_N * H_N;
  float* cbuf = (float*)(ws + 16777216 + 524288);

  pack_w_kernel<<<32768, 256, 0, stream>>>(Wx, Wh, Wp);
  hipMemsetAsync(h0, 0, B_N * H_N * sizeof(unsigned short), stream);
  hipMemsetAsync(cbuf, 0, B_N * H_N * sizeof(float), stream);

  dim3 grid(64, 2);
  for (int t = 0; t < T_N; ++t) {
    unsigned short* hc = (t & 1) ? h1 : h0;
    unsigned short* hn = (t & 1) ? h0 : h1;
    step_kernel<<<grid, 256, 0, stream>>>(x, Wp, bias, hc, hn, cbuf, out,
                                          t, (int)(t == T_N - 1));
  }
}

// Round 2
// 13028.575 us; speedup vs baseline: 1.7046x; 1.7046x over previous
//
#include <hip/hip_runtime.h>
#include <hip/hip_bf16.h>

typedef __attribute__((ext_vector_type(8))) short bf16x8;
typedef __attribute__((ext_vector_type(4))) float f32x4;

#define NBLK 256
#define NTHR 512

__device__ __forceinline__ unsigned short f2bf(float f) {
  unsigned int u = __float_as_uint(f);
  unsigned int r = (u + 0x7FFFu + ((u >> 16) & 1u)) >> 16;
  return (unsigned short)r;
}

// Pack weights bf16 into per-block layout: Wp[jb 128][c 32][k 2048],
// c = jj*4 + g (j = jb*8 + jj; gate order i,f,o,u), k<1024 -> Wh, else Wx.
__global__ __launch_bounds__(256) void pack_w(const float* __restrict__ Wx,
                                              const float* __restrict__ Wh,
                                              unsigned short* __restrict__ Wp) {
  int idx = blockIdx.x * 256 + threadIdx.x;     // 8,388,608 total
  int k  = idx & 2047;
  int c  = (idx >> 11) & 31;
  int jb = idx >> 16;
  int g  = c & 3;
  int j  = jb * 8 + (c >> 2);
  float v = (k < 1024) ? Wh[((size_t)(g * 1024 + k)) * 1024 + j]
                       : Wx[((size_t)(g * 1024 + (k - 1024))) * 1024 + j];
  Wp[idx] = f2bf(v);
}

__device__ __forceinline__ void gridbar(unsigned* bar, unsigned t) {
  __syncthreads();   // drains each wave's vmcnt -> all h stores are in L2
  if (threadIdx.x == 0) {
    unsigned* cnt = bar;
    unsigned* gen = bar + 32;   // different cache line
    __builtin_amdgcn_fence(__ATOMIC_RELEASE, "agent");
    unsigned prev = __hip_atomic_fetch_add(cnt, 1u, __ATOMIC_ACQ_REL, __HIP_MEMORY_SCOPE_AGENT);
    if (prev == NBLK - 1) {
      __hip_atomic_store(cnt, 0u, __ATOMIC_RELAXED, __HIP_MEMORY_SCOPE_AGENT);
      __hip_atomic_fetch_add(gen, 1u, __ATOMIC_RELEASE, __HIP_MEMORY_SCOPE_AGENT);
    } else {
      while (__hip_atomic_load(gen, __ATOMIC_RELAXED, __HIP_MEMORY_SCOPE_AGENT) <= t)
        __builtin_amdgcn_s_sleep(2);
    }
    __builtin_amdgcn_fence(__ATOMIC_ACQUIRE, "agent");  // inv L1/L2 before reading new h
  }
  __syncthreads();
}

// Persistent LSTM: block = 64 batch rows x 8 h-cols (32 gate cols).
// Weights LDS-resident for all 512 steps. 8 waves = 4 row-tiles x 2 K-parities.
__global__ __launch_bounds__(512) void lstm_persist(
    const float* __restrict__ x,
    const unsigned short* __restrict__ Wp,
    const float* __restrict__ bias,
    unsigned short* __restrict__ h0,
    unsigned short* __restrict__ h1,
    float* __restrict__ out,
    unsigned* __restrict__ bar)
{
  __shared__ unsigned short Wlds[32][2052];   // 131,328 B (pad: even bank spread)
  __shared__ float gt[2][64][33];             // 16,896 B  (+1 pad col)

  const int tid = threadIdx.x;
  const int bx  = blockIdx.x;
  // XCD-aware: blocks on XCDs 0-3 take rows 0-63, XCDs 4-7 rows 64-127
  const int xcd = bx & 7;
  const int rb  = xcd >> 2;
  const int jb  = (bx >> 3) * 4 + (xcd & 3);   // bijective over 0..127
  const int row0 = rb * 64;

  // ---- load this block's weight slice into LDS (once)
  #pragma unroll
  for (int rep = 0; rep < 16; ++rep) {
    int ch = rep * 512 + tid;                 // 8192 chunks of 8 bf16
    int c  = ch >> 8;
    int k8 = (ch & 255) * 8;
    *(bf16x8*)&Wlds[c][k8] = *(const bf16x8*)(Wp + ((size_t)(jb * 32 + c)) * 2048 + k8);
  }

  const int lane = tid & 63;
  const int w    = tid >> 6;     // 0..7
  const int wr   = w >> 1;       // row tile 0..3 (16 rows each)
  const int wn   = w & 1;        // K-parity
  const int a15  = lane & 15;
  const int hi   = lane >> 4;

  // per-thread elementwise item: (um, uj)
  const int um  = tid >> 3;                  // 0..63 row within block
  const int uj  = tid & 7;                   // 0..7 j within block
  const int ujg = jb * 8 + uj;               // global j
  const float bi = bias[ujg], bf_ = bias[1024 + ujg];
  const float bo = bias[2048 + ujg], bu = bias[3072 + ujg];
  float creg = 0.f;

  const int rowg = row0 + wr * 16 + a15;     // A-fragment row this lane loads
  const float* xrow = x + (size_t)rowg * 512 * 1024;

  __syncthreads();

  unsigned short* hb[2] = {h0, h1};

  for (int t = 0; t < 512; ++t) {
    const unsigned short* hc = hb[t & 1];
    unsigned short* hn = hb[(t + 1) & 1];

    f32x4 acc0 = {}, acc1 = {};

    // ---- h half: ksteps {2s+wn}, k = kstep*32 (< 1024)
    const bf16x8* hrow = (const bf16x8*)(hc + (size_t)rowg * 1024) + hi;
    #pragma unroll 4
    for (int s = 0; s < 16; ++s) {
      const int kstep = 2 * s + wn;
      bf16x8 af = hrow[kstep * 4];
      bf16x8 b0 = *(const bf16x8*)&Wlds[a15][kstep * 32 + hi * 8];
      bf16x8 b1 = *(const bf16x8*)&Wlds[16 + a15][kstep * 32 + hi * 8];
      acc0 = __builtin_amdgcn_mfma_f32_16x16x32_bf16(af, b0, acc0, 0, 0, 0);
      acc1 = __builtin_amdgcn_mfma_f32_16x16x32_bf16(af, b1, acc1, 0, 0, 0);
    }
    // ---- x half: k = 1024 + kstep*32, f32 -> bf16 in flight
    const float* xt = xrow + (size_t)t * 1024 + hi * 8;
    #pragma unroll 4
    for (int s = 0; s < 16; ++s) {
      const int kstep = 2 * s + wn;
      const float* xp = xt + kstep * 32;
      float4 f0 = *(const float4*)xp;
      float4 f1 = *(const float4*)(xp + 4);
      float fl[8] = {f0.x, f0.y, f0.z, f0.w, f1.x, f1.y, f1.z, f1.w};
      union { bf16x8 v; unsigned short us[8]; } u;
      #pragma unroll
      for (int e = 0; e < 8; ++e)
        u.us[e] = __builtin_bit_cast(unsigned short, __float2bfloat16(fl[e]));
      const int kk = 1024 + kstep * 32 + hi * 8;
      bf16x8 b0 = *(const bf16x8*)&Wlds[a15][kk];
      bf16x8 b1 = *(const bf16x8*)&Wlds[16 + a15][kk];
      acc0 = __builtin_amdgcn_mfma_f32_16x16x32_bf16(u.v, b0, acc0, 0, 0, 0);
      acc1 = __builtin_amdgcn_mfma_f32_16x16x32_bf16(u.v, b1, acc1, 0, 0, 0);
    }

    // ---- exchange partial gates (two K-halves) through LDS
    #pragma unroll
    for (int r = 0; r < 4; ++r) {
      gt[wn][wr * 16 + hi * 4 + r][a15]      = acc0[r];
      gt[wn][wr * 16 + hi * 4 + r][16 + a15] = acc1[r];
    }
    __syncthreads();

    // ---- elementwise LSTM update: one (row, j) per thread
    float vi = gt[0][um][uj * 4 + 0] + gt[1][um][uj * 4 + 0] + bi;
    float vf = gt[0][um][uj * 4 + 1] + gt[1][um][uj * 4 + 1] + bf_;
    float vo = gt[0][um][uj * 4 + 2] + gt[1][um][uj * 4 + 2] + bo;
    float vu = gt[0][um][uj * 4 + 3] + gt[1][um][uj * 4 + 3] + bu;
    float iv = 1.f / (1.f + expf(-vi));
    float fv = 1.f / (1.f + expf(-vf));
    float ov = 1.f / (1.f + expf(-vo));
    float uv = tanhf(vu);
    creg = fv * creg + iv * uv;
    float hv = ov * tanhf(creg);
    hn[(size_t)(row0 + um) * 1024 + ujg] = f2bf(hv);
    if (t == 511) out[(size_t)(row0 + um) * 1024 + ujg] = hv;

    if (t < 511) gridbar(bar, (unsigned)t);
  }
}

extern "C" void kernel_launch(void* const* d_in, const int* in_sizes, int n_in,
                              void* d_out, int out_size, void* d_ws, size_t ws_size,
                              hipStream_t stream) {
  const float* x    = (const float*)d_in[0];
  // d_in[1] = adjacency (unused)
  const float* Wx   = (const float*)d_in[2];
  const float* Wh   = (const float*)d_in[3];
  const float* bias = (const float*)d_in[4];
  float* out = (float*)d_out;

  // ws: Wp 16 MB | h0 256 KB | h1 256 KB | barrier 256 B
  char* ws = (char*)d_ws;
  unsigned short* Wp = (unsigned short*)ws;
  unsigned short* h0 = (unsigned short*)(ws + 16777216);
  unsigned short* h1 = h0 + 128 * 1024;
  unsigned* bar = (unsigned*)(ws + 16777216 + 2 * 262144);

  pack_w<<<32768, 256, 0, stream>>>(Wx, Wh, Wp);
  hipMemsetAsync(h0, 0, 128 * 1024 * sizeof(unsigned short), stream);
  hipMemsetAsync(bar, 0, 256, stream);

  void* xs = (void*)x;  // silence unused in_sizes/n_in/ws_size warnings
  (void)xs; (void)in_sizes; (void)n_in; (void)ws_size;

  lstm_persist<<<NBLK, NTHR, 0, stream>>>(x, Wp, bias, h0, h1, out, bar);
}

// Round 3
// 4617.922 us; speedup vs baseline: 4.8092x; 2.8213x over previous
//
#include <hip/hip_runtime.h>
#include <hip/hip_bf16.h>

typedef __attribute__((ext_vector_type(8))) short bf16x8;
typedef __attribute__((ext_vector_type(4))) float f32x4;

#define NBLK 256
#define NTHR 512

__device__ __forceinline__ unsigned short f2bf(float f) {
  unsigned int u = __float_as_uint(f);
  unsigned int r = (u + 0x7FFFu + ((u >> 16) & 1u)) >> 16;
  return (unsigned short)r;
}

// coherence-point (bypass L1/L2) ops for the h exchange
__device__ __forceinline__ bf16x8 ldg_b128_coh(const unsigned short* p) {
  bf16x8 r;
  asm volatile("global_load_dwordx4 %0, %1, off sc0 sc1"
               : "=v"(r) : "v"(p) : "memory");
  return r;
}
__device__ __forceinline__ void stg_b16_coh(unsigned short* p, unsigned v) {
  asm volatile("global_store_short %0, %1, off sc0 sc1"
               :: "v"(p), "v"(v) : "memory");
}

// Pack weights bf16: Wp[jb 128][c 32][k 2048], c = jj*4 + g.
__global__ __launch_bounds__(256) void pack_w(const float* __restrict__ Wx,
                                              const float* __restrict__ Wh,
                                              unsigned short* __restrict__ Wp) {
  int idx = blockIdx.x * 256 + threadIdx.x;
  int k  = idx & 2047;
  int c  = (idx >> 11) & 31;
  int jb = idx >> 16;
  int g  = c & 3;
  int j  = jb * 8 + (c >> 2);
  float v = (k < 1024) ? Wh[((size_t)(g * 1024 + k)) * 1024 + j]
                       : Wx[((size_t)(g * 1024 + (k - 1024))) * 1024 + j];
  Wp[idx] = f2bf(v);
}

// Pack x to bf16 in per-wave A-fragment order:
// flat = (((t*2+rb)*2+wn)*16+s)*2048 + (wr*64+lane)*8 + e
__global__ __launch_bounds__(256) void pack_x(const float* __restrict__ x,
                                              unsigned short* __restrict__ xpk) {
  size_t idx = (size_t)blockIdx.x * 256 + threadIdx.x;   // 8,388,608 chunks of 8
  int lane = (int)(idx & 63);
  int wr   = (int)((idx >> 6) & 3);
  int s    = (int)((idx >> 8) & 15);
  int wn   = (int)((idx >> 12) & 1);
  int rb   = (int)((idx >> 13) & 1);
  int t    = (int)(idx >> 14);
  int a15 = lane & 15, hi = lane >> 4;
  int row = rb * 64 + wr * 16 + a15;
  int k   = (2 * s + wn) * 32 + hi * 8;
  const float* src = x + ((size_t)row * 512 + t) * 1024 + k;
  float4 f0 = *(const float4*)src;
  float4 f1 = *(const float4*)(src + 4);
  float fl[8] = {f0.x, f0.y, f0.z, f0.w, f1.x, f1.y, f1.z, f1.w};
  union { bf16x8 v; unsigned short us[8]; } u;
  #pragma unroll
  for (int e = 0; e < 8; ++e) u.us[e] = f2bf(fl[e]);
  *(bf16x8*)(xpk + idx * 8) = u.v;
}

__global__ __launch_bounds__(512, 2) void lstm_persist(
    const float* __restrict__ x,
    const unsigned short* __restrict__ xpk,   // may be null -> f32 fallback
    const unsigned short* __restrict__ Wp,
    const float* __restrict__ bias,
    unsigned short* __restrict__ h0,
    unsigned short* __restrict__ h1,
    float* __restrict__ out,
    unsigned* __restrict__ bar)
{
  __shared__ unsigned short Wlds[32][2052];   // 131,328 B
  __shared__ float gt[2][64][33];             // 16,896 B

  const int tid = threadIdx.x;
  const int bx  = blockIdx.x;
  const int xcd = bx & 7;
  const int rb  = xcd >> 2;
  const int jb  = (bx >> 3) * 4 + (xcd & 3);
  const int row0 = rb * 64;

  // weight slice -> LDS (once)
  #pragma unroll
  for (int rep = 0; rep < 16; ++rep) {
    int ch = rep * 512 + tid;
    int c  = ch >> 8;
    int k8 = (ch & 255) * 8;
    *(bf16x8*)&Wlds[c][k8] = *(const bf16x8*)(Wp + ((size_t)(jb * 32 + c)) * 2048 + k8);
  }

  const int lane = tid & 63;
  const int w    = tid >> 6;
  const int wr   = w >> 1;
  const int wn   = w & 1;
  const int a15  = lane & 15;
  const int hi   = lane >> 4;

  const int um  = tid >> 3;
  const int uj  = tid & 7;
  const int ujg = jb * 8 + uj;
  const float bi = bias[ujg], bf_ = bias[1024 + ujg];
  const float bo = bias[2048 + ujg], bu = bias[3072 + ujg];
  float creg = 0.f;

  const int rowg = row0 + wr * 16 + a15;
  const float* xrow = x + (size_t)rowg * 512 * 1024;
  const size_t xpk_lane = ((size_t)wr * 64 + lane) * 8;

  __syncthreads();

  unsigned short* hb[2] = {h0, h1};
  bf16x8 xreg[16];

  // prologue: prefetch x fragments for t=0
  if (xpk) {
    const unsigned short* xs = xpk + ((((size_t)0 * 2 + rb) * 2 + wn) * 16) * 2048 + xpk_lane;
    #pragma unroll
    for (int s = 0; s < 16; ++s) {
      const unsigned short* p = xs + s * 2048;
      asm volatile("global_load_dwordx4 %0, %1, off" : "=v"(xreg[s]) : "v"(p) : "memory");
    }
  } else {
    const float* xt = xrow + hi * 8;
    #pragma unroll
    for (int s = 0; s < 16; ++s) {
      const float* xp = xt + (2 * s + wn) * 32;
      float4 f0 = *(const float4*)xp;
      float4 f1 = *(const float4*)(xp + 4);
      float fl[8] = {f0.x, f0.y, f0.z, f0.w, f1.x, f1.y, f1.z, f1.w};
      union { bf16x8 v; unsigned short us[8]; } u;
      #pragma unroll
      for (int e = 0; e < 8; ++e) u.us[e] = f2bf(fl[e]);
      xreg[s] = u.v;
    }
  }

  for (int t = 0; t < 512; ++t) {
    const unsigned short* hc = hb[t & 1];
    unsigned short* hn = hb[(t + 1) & 1];

    f32x4 acc0 = {}, acc1 = {};

    // phase 1: issue all 16 h loads (coherent bypass)
    bf16x8 hreg[16];
    const unsigned short* hbase = hc + (size_t)rowg * 1024 + hi * 8;
    #pragma unroll
    for (int s = 0; s < 16; ++s)
      hreg[s] = ldg_b128_coh(hbase + (2 * s + wn) * 32);

    // phase 2: drain xreg only (16 h loads stay in flight), then x MFMAs
    asm volatile("s_waitcnt vmcnt(16)" ::: "memory");
    __builtin_amdgcn_sched_barrier(0);
    #pragma unroll
    for (int s = 0; s < 16; ++s) {
      const int kk = 1024 + (2 * s + wn) * 32 + hi * 8;
      bf16x8 b0 = *(const bf16x8*)&Wlds[a15][kk];
      bf16x8 b1 = *(const bf16x8*)&Wlds[16 + a15][kk];
      acc0 = __builtin_amdgcn_mfma_f32_16x16x32_bf16(xreg[s], b0, acc0, 0, 0, 0);
      acc1 = __builtin_amdgcn_mfma_f32_16x16x32_bf16(xreg[s], b1, acc1, 0, 0, 0);
    }

    // phase 3: drain h loads, h MFMAs
    asm volatile("s_waitcnt vmcnt(0)" ::: "memory");
    __builtin_amdgcn_sched_barrier(0);
    #pragma unroll
    for (int s = 0; s < 16; ++s) {
      const int kk = (2 * s + wn) * 32 + hi * 8;
      bf16x8 b0 = *(const bf16x8*)&Wlds[a15][kk];
      bf16x8 b1 = *(const bf16x8*)&Wlds[16 + a15][kk];
      acc0 = __builtin_amdgcn_mfma_f32_16x16x32_bf16(hreg[s], b0, acc0, 0, 0, 0);
      acc1 = __builtin_amdgcn_mfma_f32_16x16x32_bf16(hreg[s], b1, acc1, 0, 0, 0);
    }

    // phase 4: gate exchange through LDS
    #pragma unroll
    for (int r = 0; r < 4; ++r) {
      gt[wn][wr * 16 + hi * 4 + r][a15]      = acc0[r];
      gt[wn][wr * 16 + hi * 4 + r][16 + a15] = acc1[r];
    }
    __syncthreads();   // nothing vm-outstanding except nothing; drains lgkm for gt

    // phase 5: elementwise LSTM update
    float vi = gt[0][um][uj * 4 + 0] + gt[1][um][uj * 4 + 0] + bi;
    float vf = gt[0][um][uj * 4 + 1] + gt[1][um][uj * 4 + 1] + bf_;
    float vo = gt[0][um][uj * 4 + 2] + gt[1][um][uj * 4 + 2] + bo;
    float vu = gt[0][um][uj * 4 + 3] + gt[1][um][uj * 4 + 3] + bu;
    float iv = 1.f / (1.f + expf(-vi));
    float fv = 1.f / (1.f + expf(-vf));
    float ov = 1.f / (1.f + expf(-vo));
    float uv = tanhf(vu);
    creg = fv * creg + iv * uv;
    float hv = ov * tanhf(creg);
    stg_b16_coh(hn + (size_t)(row0 + um) * 1024 + ujg, (unsigned)f2bf(hv));
    if (t == 511) {
      out[(size_t)(row0 + um) * 1024 + ujg] = hv;
      break;
    }

    // phase 6: prefetch x for t+1 (AFTER the h store, so counted drain works)
    if (xpk) {
      const unsigned short* xs = xpk + ((((size_t)(t + 1) * 2 + rb) * 2 + wn) * 16) * 2048 + xpk_lane;
      #pragma unroll
      for (int s = 0; s < 16; ++s) {
        const unsigned short* p = xs + s * 2048;
        asm volatile("global_load_dwordx4 %0, %1, off" : "=v"(xreg[s]) : "v"(p) : "memory");
      }
    } else {
      const float* xt = xrow + (size_t)(t + 1) * 1024 + hi * 8;
      #pragma unroll
      for (int s = 0; s < 16; ++s) {
        const float* xp = xt + (2 * s + wn) * 32;
        float4 f0 = *(const float4*)xp;
        float4 f1 = *(const float4*)(xp + 4);
        float fl[8] = {f0.x, f0.y, f0.z, f0.w, f1.x, f1.y, f1.z, f1.w};
        union { bf16x8 v; unsigned short us[8]; } u;
        #pragma unroll
        for (int e = 0; e < 8; ++e) u.us[e] = f2bf(fl[e]);
        xreg[s] = u.v;
      }
    }

    // phase 7: grid barrier. Drain only the h store (x prefetch stays in flight).
    asm volatile("s_waitcnt vmcnt(16)" ::: "memory");
    __builtin_amdgcn_s_barrier();          // all waves stored h & arrived
    if (tid == 0) {
      unsigned g = (unsigned)(bx & 7);
      unsigned prev = __hip_atomic_fetch_add(&bar[g * 32], 1u, __ATOMIC_RELAXED,
                                             __HIP_MEMORY_SCOPE_AGENT);
      if ((prev & 31u) == 31u) {           // last of this group's 32 for this step
        unsigned rp = __hip_atomic_fetch_add(&bar[256], 1u, __ATOMIC_RELAXED,
                                             __HIP_MEMORY_SCOPE_AGENT);
        if ((rp & 7u) == 7u)               // last group
          __hip_atomic_fetch_add(&bar[320], 1u, __ATOMIC_RELAXED,
                                 __HIP_MEMORY_SCOPE_AGENT);
      }
      while (__hip_atomic_load(&bar[320], __ATOMIC_RELAXED,
                               __HIP_MEMORY_SCOPE_AGENT) <= (unsigned)t)
        __builtin_amdgcn_s_sleep(4);
    }
    __builtin_amdgcn_s_barrier();          // release
  }
}

extern "C" void kernel_launch(void* const* d_in, const int* in_sizes, int n_in,
                              void* d_out, int out_size, void* d_ws, size_t ws_size,
                              hipStream_t stream) {
  const float* x    = (const float*)d_in[0];
  // d_in[1] = adjacency (unused)
  const float* Wx   = (const float*)d_in[2];
  const float* Wh   = (const float*)d_in[3];
  const float* bias = (const float*)d_in[4];
  float* out = (float*)d_out;

  // ws: Wp 16MB | h0 | h1 | bar | (xpk @ 32MB, 134MB)
  char* ws = (char*)d_ws;
  unsigned short* Wp = (unsigned short*)ws;
  unsigned short* h0 = (unsigned short*)(ws + 16777216);
  unsigned short* h1 = h0 + 128 * 1024;
  unsigned* bar = (unsigned*)(ws + 16777216 + 2 * 262144);
  const size_t XPK_OFF = 33554432;
  const size_t XPK_SZ  = 134217728;
  unsigned short* xpk = (ws_size >= XPK_OFF + XPK_SZ)
                        ? (unsigned short*)(ws + XPK_OFF) : nullptr;

  pack_w<<<32768, 256, 0, stream>>>(Wx, Wh, Wp);
  if (xpk) pack_x<<<32768, 256, 0, stream>>>(x, xpk);
  hipMemsetAsync(h0, 0, 128 * 1024 * sizeof(unsigned short), stream);
  hipMemsetAsync(bar, 0, 2048, stream);

  (void)in_sizes; (void)n_in;
  lstm_persist<<<NBLK, NTHR, 0, stream>>>(x, xpk, Wp, bias, h0, h1, out, bar);
}

// Round 4
// 3797.371 us; speedup vs baseline: 5.8484x; 1.2161x over previous
//
#include <hip/hip_runtime.h>
#include <hip/hip_bf16.h>

typedef __attribute__((ext_vector_type(8))) short bf16x8;
typedef __attribute__((ext_vector_type(4))) float f32x4;
typedef __attribute__((ext_vector_type(2))) unsigned uint32x2;

#define NBLK 256
#define NTHR 512

__device__ __forceinline__ unsigned short f2bf(float f) {
  unsigned int u = __float_as_uint(f);
  unsigned int r = (u + 0x7FFFu + ((u >> 16) & 1u)) >> 16;
  return (unsigned short)r;
}

// coherence-point (bypass L1/L2) ops for the h exchange
__device__ __forceinline__ bf16x8 ldg_b128_coh(const unsigned short* p) {
  bf16x8 r;
  asm volatile("global_load_dwordx4 %0, %1, off sc0 sc1"
               : "=v"(r) : "v"(p) : "memory");
  return r;
}
__device__ __forceinline__ void stg_b16_coh(unsigned short* p, unsigned v) {
  asm volatile("global_store_short %0, %1, off sc0 sc1"
               :: "v"(p), "v"(v) : "memory");
}

// Pack weights bf16: Wp[jb 128][c 32][k 2048], c = jj*4 + g.
__global__ __launch_bounds__(256) void pack_w(const float* __restrict__ Wx,
                                              const float* __restrict__ Wh,
                                              unsigned short* __restrict__ Wp) {
  int idx = blockIdx.x * 256 + threadIdx.x;
  int k  = idx & 2047;
  int c  = (idx >> 11) & 31;
  int jb = idx >> 16;
  int g  = c & 3;
  int j  = jb * 8 + (c >> 2);
  float v = (k < 1024) ? Wh[((size_t)(g * 1024 + k)) * 1024 + j]
                       : Wx[((size_t)(g * 1024 + (k - 1024))) * 1024 + j];
  Wp[idx] = f2bf(v);
}

// Pack x to bf16 in per-wave A-fragment order:
// flat = (((t*2+rb)*2+wn)*16+s)*2048 + (wr*64+lane)*8 + e
__global__ __launch_bounds__(256) void pack_x(const float* __restrict__ x,
                                              unsigned short* __restrict__ xpk) {
  size_t idx = (size_t)blockIdx.x * 256 + threadIdx.x;   // 8,388,608 chunks of 8
  int lane = (int)(idx & 63);
  int wr   = (int)((idx >> 6) & 3);
  int s    = (int)((idx >> 8) & 15);
  int wn   = (int)((idx >> 12) & 1);
  int rb   = (int)((idx >> 13) & 1);
  int t    = (int)(idx >> 14);
  int a15 = lane & 15, hi = lane >> 4;
  int row = rb * 64 + wr * 16 + a15;
  int k   = (2 * s + wn) * 32 + hi * 8;
  const float* src = x + ((size_t)row * 512 + t) * 1024 + k;
  float4 f0 = *(const float4*)src;
  float4 f1 = *(const float4*)(src + 4);
  float fl[8] = {f0.x, f0.y, f0.z, f0.w, f1.x, f1.y, f1.z, f1.w};
  union { bf16x8 v; unsigned short us[8]; } u;
  #pragma unroll
  for (int e = 0; e < 8; ++e) u.us[e] = f2bf(fl[e]);
  *(bf16x8*)(xpk + idx * 8) = u.v;
}

__global__ __launch_bounds__(512, 2) void lstm_persist(
    const float* __restrict__ x,
    const unsigned short* __restrict__ xpk,   // may be null -> f32 fallback
    const unsigned short* __restrict__ Wp,
    const float* __restrict__ bias,
    unsigned short* __restrict__ h0,
    unsigned short* __restrict__ h1,
    float* __restrict__ out,
    unsigned* __restrict__ bar)   // bar[rb*128 + jb] = step flags
{
  __shared__ unsigned short Wlds[32][2052];   // 131,328 B
  __shared__ float gt[2][64][33];             // 16,896 B

  const int tid = threadIdx.x;
  const int bx  = blockIdx.x;
  const int xcd = bx & 7;
  const int rb  = xcd >> 2;
  const int jb  = (bx >> 3) * 4 + (xcd & 3);   // 0..127, bijective with rb
  const int row0 = rb * 64;

  // weight slice -> LDS (once)
  #pragma unroll
  for (int rep = 0; rep < 16; ++rep) {
    int ch = rep * 512 + tid;
    int c  = ch >> 8;
    int k8 = (ch & 255) * 8;
    *(bf16x8*)&Wlds[c][k8] = *(const bf16x8*)(Wp + ((size_t)(jb * 32 + c)) * 2048 + k8);
  }

  const int lane = tid & 63;
  const int w    = tid >> 6;
  const int wr   = w >> 1;
  const int wn   = w & 1;
  const int a15  = lane & 15;
  const int hi   = lane >> 4;

  const int um  = tid >> 3;
  const int uj  = tid & 7;
  const int ujg = jb * 8 + uj;
  const float bi = bias[ujg], bf_ = bias[1024 + ujg];
  const float bo = bias[2048 + ujg], bu = bias[3072 + ujg];
  float creg = 0.f;

  const int rowg = row0 + wr * 16 + a15;
  const float* xrow = x + (size_t)rowg * 512 * 1024;
  const size_t xpk_lane = ((size_t)wr * 64 + lane) * 8;
  const unsigned* fpoll = bar + rb * 128 + (lane << 1);   // dwordx2 per lane covers 128 flags

  __syncthreads();

  unsigned short* hb[2] = {h0, h1};
  bf16x8 xreg[16];

  // prologue: x fragments for t=0, fully drained
  if (xpk) {
    const unsigned short* xs = xpk + (((size_t)0 * 2 + rb) * 2 + wn) * 16 * 2048 + xpk_lane;
    #pragma unroll
    for (int s = 0; s < 16; ++s)
      asm volatile("global_load_dwordx4 %0, %1, off" : "=v"(xreg[s]) : "v"(xs + s * 2048) : "memory");
    asm volatile("s_waitcnt vmcnt(0)" ::: "memory");
    __builtin_amdgcn_sched_barrier(0);
  } else {
    const float* xt = xrow + hi * 8;
    #pragma unroll
    for (int s = 0; s < 16; ++s) {
      const float* xp = xt + (2 * s + wn) * 32;
      float4 f0 = *(const float4*)xp;
      float4 f1 = *(const float4*)(xp + 4);
      float fl[8] = {f0.x, f0.y, f0.z, f0.w, f1.x, f1.y, f1.z, f1.w};
      union { bf16x8 v; unsigned short us[8]; } u;
      #pragma unroll
      for (int e = 0; e < 8; ++e) u.us[e] = f2bf(fl[e]);
      xreg[s] = u.v;
    }
  }

  for (int t = 0; t < 512; ++t) {
    const unsigned short* hc = hb[t & 1];
    unsigned short* hn = hb[(t + 1) & 1];

    // phase 1: issue all 16 h loads (coherent bypass). h[t] is ready:
    // t=0 via memset, t>0 via the poll at the end of the previous step.
    bf16x8 hreg[16];
    const unsigned short* hbase = hc + (size_t)rowg * 1024 + hi * 8;
    #pragma unroll
    for (int s = 0; s < 16; ++s)
      hreg[s] = ldg_b128_coh(hbase + (2 * s + wn) * 32);
    __builtin_amdgcn_sched_barrier(0);

    // phase 2: x MFMAs (xreg already resident; h loads in flight under them)
    f32x4 acc0 = {}, acc1 = {};
    #pragma unroll
    for (int s = 0; s < 16; ++s) {
      const int kk = 1024 + (2 * s + wn) * 32 + hi * 8;
      bf16x8 b0 = *(const bf16x8*)&Wlds[a15][kk];
      bf16x8 b1 = *(const bf16x8*)&Wlds[16 + a15][kk];
      acc0 = __builtin_amdgcn_mfma_f32_16x16x32_bf16(xreg[s], b0, acc0, 0, 0, 0);
      acc1 = __builtin_amdgcn_mfma_f32_16x16x32_bf16(xreg[s], b1, acc1, 0, 0, 0);
    }

    // phase 3: h MFMAs with split counted waits (oldest 8 first)
    asm volatile("s_waitcnt vmcnt(8)" ::: "memory");
    __builtin_amdgcn_sched_barrier(0);
    #pragma unroll
    for (int s = 0; s < 8; ++s) {
      const int kk = (2 * s + wn) * 32 + hi * 8;
      bf16x8 b0 = *(const bf16x8*)&Wlds[a15][kk];
      bf16x8 b1 = *(const bf16x8*)&Wlds[16 + a15][kk];
      acc0 = __builtin_amdgcn_mfma_f32_16x16x32_bf16(hreg[s], b0, acc0, 0, 0, 0);
      acc1 = __builtin_amdgcn_mfma_f32_16x16x32_bf16(hreg[s], b1, acc1, 0, 0, 0);
    }
    asm volatile("s_waitcnt vmcnt(0)" ::: "memory");
    __builtin_amdgcn_sched_barrier(0);
    #pragma unroll
    for (int s = 8; s < 16; ++s) {
      const int kk = (2 * s + wn) * 32 + hi * 8;
      bf16x8 b0 = *(const bf16x8*)&Wlds[a15][kk];
      bf16x8 b1 = *(const bf16x8*)&Wlds[16 + a15][kk];
      acc0 = __builtin_amdgcn_mfma_f32_16x16x32_bf16(hreg[s], b0, acc0, 0, 0, 0);
      acc1 = __builtin_amdgcn_mfma_f32_16x16x32_bf16(hreg[s], b1, acc1, 0, 0, 0);
    }

    // phase 4: gate exchange through LDS
    #pragma unroll
    for (int r = 0; r < 4; ++r) {
      gt[wn][wr * 16 + hi * 4 + r][a15]      = acc0[r];
      gt[wn][wr * 16 + hi * 4 + r][16 + a15] = acc1[r];
    }
    __syncthreads();

    // phase 5: elementwise LSTM update + coherent h store
    float vi = gt[0][um][uj * 4 + 0] + gt[1][um][uj * 4 + 0] + bi;
    float vf = gt[0][um][uj * 4 + 1] + gt[1][um][uj * 4 + 1] + bf_;
    float vo = gt[0][um][uj * 4 + 2] + gt[1][um][uj * 4 + 2] + bo;
    float vu = gt[0][um][uj * 4 + 3] + gt[1][um][uj * 4 + 3] + bu;
    float iv = 1.f / (1.f + expf(-vi));
    float fv = 1.f / (1.f + expf(-vf));
    float ov = 1.f / (1.f + expf(-vo));
    float uv = tanhf(vu);
    creg = fv * creg + iv * uv;
    float hv = ov * tanhf(creg);
    stg_b16_coh(hn + (size_t)(row0 + um) * 1024 + ujg, (unsigned)f2bf(hv));
    if (t == 511) {
      out[(size_t)(row0 + um) * 1024 + ujg] = hv;
      break;
    }

    // phase 6: drain h store, block-local barrier, publish arrival flag
    asm volatile("s_waitcnt vmcnt(0)" ::: "memory");
    __builtin_amdgcn_s_barrier();
    if (tid == 0) {
      const unsigned* p = bar + rb * 128 + jb;
      unsigned val = (unsigned)(t + 1);
      asm volatile("global_store_dword %0, %1, off sc0 sc1"
                   :: "v"(p), "v"(val) : "memory");
    }

    // phase 7: issue x[t+1] prefetch (latency hides under the poll)
    if (xpk) {
      const unsigned short* xs = xpk + (((size_t)(t + 1) * 2 + rb) * 2 + wn) * 16 * 2048 + xpk_lane;
      #pragma unroll
      for (int s = 0; s < 16; ++s)
        asm volatile("global_load_dwordx4 %0, %1, off" : "=v"(xreg[s]) : "v"(xs + s * 2048) : "memory");
    } else {
      const float* xt = xrow + (size_t)(t + 1) * 1024 + hi * 8;
      #pragma unroll
      for (int s = 0; s < 16; ++s) {
        const float* xp = xt + (2 * s + wn) * 32;
        float4 f0 = *(const float4*)xp;
        float4 f1 = *(const float4*)(xp + 4);
        float fl[8] = {f0.x, f0.y, f0.z, f0.w, f1.x, f1.y, f1.z, f1.w};
        union { bf16x8 v; unsigned short us[8]; } u;
        #pragma unroll
        for (int e = 0; e < 8; ++e) u.us[e] = f2bf(fl[e]);
        xreg[s] = u.v;
      }
    }

    // phase 8: every wave polls its group's 128 flags (one dwordx2 per lane).
    // The vmcnt(0) inside the poll also drains the x prefetch.
    for (;;) {
      uint32x2 v;
      asm volatile("global_load_dwordx2 %0, %1, off sc0 sc1"
                   : "=v"(v) : "v"(fpoll) : "memory");
      asm volatile("s_waitcnt vmcnt(0)" ::: "memory");
      if (__all(v.x > (unsigned)t && v.y > (unsigned)t)) break;
      __builtin_amdgcn_s_sleep(1);
    }
    __builtin_amdgcn_sched_barrier(0);
  }
}

extern "C" void kernel_launch(void* const* d_in, const int* in_sizes, int n_in,
                              void* d_out, int out_size, void* d_ws, size_t ws_size,
                              hipStream_t stream) {
  const float* x    = (const float*)d_in[0];
  // d_in[1] = adjacency (unused)
  const float* Wx   = (const float*)d_in[2];
  const float* Wh   = (const float*)d_in[3];
  const float* bias = (const float*)d_in[4];
  float* out = (float*)d_out;

  // ws: Wp 16MB | h0 | h1 | bar (4KB) | (xpk @ 32MB, 134MB)
  char* ws = (char*)d_ws;
  unsigned short* Wp = (unsigned short*)ws;
  unsigned short* h0 = (unsigned short*)(ws + 16777216);
  unsigned short* h1 = h0 + 128 * 1024;
  unsigned* bar = (unsigned*)(ws + 16777216 + 2 * 262144);
  const size_t XPK_OFF = 33554432;
  const size_t XPK_SZ  = 134217728;
  unsigned short* xpk = (ws_size >= XPK_OFF + XPK_SZ)
                        ? (unsigned short*)(ws + XPK_OFF) : nullptr;

  pack_w<<<32768, 256, 0, stream>>>(Wx, Wh, Wp);
  if (xpk) pack_x<<<32768, 256, 0, stream>>>(x, xpk);
  hipMemsetAsync(h0, 0, 128 * 1024 * sizeof(unsigned short), stream);
  hipMemsetAsync(bar, 0, 4096, stream);

  (void)in_sizes; (void)n_in;
  lstm_persist<<<NBLK, NTHR, 0, stream>>>(x, xpk, Wp, bias, h0, h1, out, bar);
}